// Round 5
// baseline (577.431 us; speedup 1.0000x reference)
//
#include <hip/hip_runtime.h>

typedef unsigned short u16;
typedef unsigned int u32;
typedef __attribute__((ext_vector_type(4))) float f32x4;
typedef __bf16 bf16x8 __attribute__((ext_vector_type(8)));
typedef __attribute__((ext_vector_type(8))) unsigned short u16x8;

// ---------- small helpers ----------
__device__ __forceinline__ u16 f2bf(float x) {
    u32 u = __builtin_bit_cast(u32, x);
    u += 0x7FFFu + ((u >> 16) & 1u);   // RNE
    return (u16)(u >> 16);
}
__device__ __forceinline__ float bf2f(u16 u) {
    return __builtin_bit_cast(float, ((u32)u) << 16);
}
__device__ __forceinline__ void gld_lds16(void* lds, const void* g) {
    __builtin_amdgcn_global_load_lds(
        (const __attribute__((address_space(1))) void*)g,
        (__attribute__((address_space(3))) void*)lds, 16, 0, 0);
}

// bf16 pack locations inside an output row (u16 index into d_out viewed as u16).
// Row byte stride 201028 ≡ 4 (mod 16); "- ((row*2)&7)" u16s makes base 16B-aligned.
__device__ __forceinline__ size_t pack_base_tail(long row) {
    return (size_t)row * 100514 + 59936 - ((row * 2) & 7);
}
__device__ __forceinline__ size_t pack_base_head(long row) {
    return (size_t)row * 100514 + 20480 - ((row * 2) & 7);
}

// ---------- all f32->bf16 converts + zero-pads in one kernel ----------
__global__ __launch_bounds__(256) void cvt_all(const float* __restrict__ x,
                                               const float* __restrict__ hw,
                                               const float* __restrict__ t0a,
                                               const float* __restrict__ t1a,
                                               const float* __restrict__ t0b,
                                               const float* __restrict__ t1b,
                                               u16* __restrict__ XI, u16* __restrict__ HW,
                                               u16* __restrict__ TAB, u16* __restrict__ T0B,
                                               u16* __restrict__ T1B) {
    int b = blockIdx.x;
    const float* src; u16* dst; int n, b0, nb;
    if (b < 80)        { src = x;    dst = XI;            n = 2097152;  b0 = 0;    nb = 80;   }
    else if (b < 472)  { src = hw;   dst = HW;            n = 10242048; b0 = 80;   nb = 392;  }
    else if (b < 512)  { src = t0a;  dst = TAB;           n = 1048576;  b0 = 472;  nb = 40;   }
    else if (b < 522)  { src = t1a;  dst = TAB + 1048576; n = 262144;   b0 = 512;  nb = 10;   }
    else if (b < 2086) { src = t0b;  dst = T0B;           n = 40960000; b0 = 522;  nb = 1564; }
    else if (b < 2090) { src = t1b;  dst = T1B;           n = 65792;    b0 = 2086; nb = 4;    }
    else if (b < 2100) { src = 0;    dst = HW + 10242048; n = 243712;   b0 = 2090; nb = 10;   }
    else               { src = 0;    dst = T0B + 40960000; n = 196608;  b0 = 2100; nb = 8;    }
    int i0 = (b - b0) * 1024 + threadIdx.x * 4;
    int stride = nb * 1024;
    if (src) {
        for (int i = i0; i < n; i += stride) {
            float4 v = *(const float4*)(src + i);
            ushort4 o;
            o.x = f2bf(v.x); o.y = f2bf(v.y); o.z = f2bf(v.z); o.w = f2bf(v.w);
            *(ushort4*)(dst + i) = o;
        }
    } else {
        ushort4 z = {0, 0, 0, 0};
        for (int i = i0; i < n; i += stride) *(ushort4*)(dst + i) = z;
    }
}

// ---------- build compact row map (1 block) ----------
// rowlist[0..cnt) = masked rows asc; rowlist[cnt..2048) = unmasked rows asc.
// GEMM pad slots [cnt, cntp) thus hold real (distinct, unmasked) rows — safe.
// cntbuf: [0]=cnt, [1]=cnt padded to 256
__global__ __launch_bounds__(256) void build_map(const int* __restrict__ tgt,
                                                 int* __restrict__ rowlist,
                                                 int* __restrict__ cntbuf) {
    __shared__ int cs[257];
    int t = threadIdx.x;
    int cnt_local = 0;
    int mk[8];
#pragma unroll
    for (int k = 0; k < 8; k++) {
        int tg = tgt[t * 8 + k];
        mk[k] = (tg >= 10000 && tg < 50000) ? 1 : 0;
        cnt_local += mk[k];
    }
    cs[t + 1] = cnt_local;
    __syncthreads();
    if (t == 0) {
        cs[0] = 0;
        for (int i = 1; i <= 256; i++) cs[i] += cs[i - 1];
        cntbuf[0] = cs[256];
        cntbuf[1] = (cs[256] + 255) & ~255;
    }
    __syncthreads();
    int cnt = cs[256];
    int offm = cs[t];
    int offu = cnt + (t * 8 - cs[t]);
#pragma unroll
    for (int k = 0; k < 8; k++) {
        if (mk[k]) rowlist[offm++] = t * 8 + k;
        else       rowlist[offu++] = t * 8 + k;
    }
}

#define PH_BAR() do { __builtin_amdgcn_sched_barrier(0); __builtin_amdgcn_s_barrier(); __builtin_amdgcn_sched_barrier(0); } while (0)

// ---------- 256x256 BK=32 8-wave, 2-phase-per-K-tile pipelined NT bf16 GEMM ----------
// 4 LDS buffers; stage tile t+2 while computing tile t; vmcnt(4) retires tile t+1.
// Phase A: read B[0..3]+A[0..3] (8 ds_read_b128), stage A-half of t+2, bar, 16 MFMA, bar.
// Phase B: read A[4..7] (4), stage B-half of t+2, vmcnt(4), bar, 16 MFMA, bar.
// LDS subtile layout (R4-proven): chunk c (16B) at byte c*16 holds
// (row=(c>>6<<4)+(c&15), k8=(c>>4)&3); frag (R,kc=hi): u16 off (R>>4)*512+hi*128+(R&15)*8.
template <int TAIL>
__global__ __launch_bounds__(512, 2) void gemm256(const u16* __restrict__ A,
                                                  const u16* __restrict__ B,
                                                  u16* __restrict__ outpk,
                                                  const int* __restrict__ rowlist,
                                                  const int* __restrict__ cntbuf,
                                                  float* __restrict__ part) {
    const int m0 = blockIdx.x * 256, n0 = blockIdx.y * 256;
    if (TAIL) { if (m0 >= cntbuf[1]) return; }
    __shared__ u16 lds[4][16384];   // 4 bufs x (A 16KB + B 16KB) = 128 KiB
    const int tid = threadIdx.x;
    const int lane = tid & 63, wv = tid >> 6;
    const int wm = wv >> 2, wn = wv & 3;      // 2x4 wave grid, wave tile 128x64
    const int lr = lane & 15, hi = lane >> 4;

    const int c0 = tid, c1 = 512 + tid;
    int ga0 = m0 + ((c0 >> 6) << 4) + (c0 & 15);
    int ga1 = m0 + ((c1 >> 6) << 4) + (c1 & 15);
    const u16* sA0;
    const u16* sA1;
    if (TAIL) {
        sA0 = A + (size_t)rowlist[ga0] * 1280 + ((c0 >> 4) & 3) * 8;
        sA1 = A + (size_t)rowlist[ga1] * 1280 + ((c1 >> 4) & 3) * 8;
    } else {
        sA0 = A + (size_t)ga0 * 1024 + ((c0 >> 4) & 3) * 8;
        sA1 = A + (size_t)ga1 * 1024 + ((c1 >> 4) & 3) * 8;
    }
    const u16* sB0 = B + (size_t)(n0 + ((c0 >> 6) << 4) + (c0 & 15)) * 1024 + ((c0 >> 4) & 3) * 8;
    const u16* sB1 = B + (size_t)(n0 + ((c1 >> 6) << 4) + (c1 & 15)) * 1024 + ((c1 >> 4) & 3) * 8;

    f32x4 acc[8][4] = {};
    bf16x8 Bf[4], Af[4];

    auto stageA = [&](int buf, int kt) {
        char* d = (char*)&lds[buf][0] + tid * 16;
        gld_lds16(d,        sA0 + kt);
        gld_lds16(d + 8192, sA1 + kt);
    };
    auto stageB = [&](int buf, int kt) {
        char* d = (char*)&lds[buf][0] + tid * 16;
        gld_lds16(d + 16384, sB0 + kt);
        gld_lds16(d + 24576, sB1 + kt);
    };
    auto readB = [&](const u16* L) {
#pragma unroll
        for (int j = 0; j < 4; j++)
            Bf[j] = *(const bf16x8*)(L + 8192 + (wn * 4 + j) * 512 + hi * 128 + lr * 8);
    };
    auto readA = [&](const u16* L, int q) {
#pragma unroll
        for (int m = 0; m < 4; m++)
            Af[m] = *(const bf16x8*)(L + (wm * 8 + q * 4 + m) * 512 + hi * 128 + lr * 8);
    };
    auto mfma16 = [&](int q) {
        __builtin_amdgcn_s_setprio(1);
#pragma unroll
        for (int m = 0; m < 4; m++)
#pragma unroll
            for (int j = 0; j < 4; j++)
                acc[q * 4 + m][j] = __builtin_amdgcn_mfma_f32_16x16x32_bf16(Af[m], Bf[j], acc[q * 4 + m][j], 0, 0, 0);
        __builtin_amdgcn_s_setprio(0);
    };

    // prologue: tiles 0,1 staged; vmcnt(4) -> tile 0 resident
    stageA(0, 0);  stageB(0, 0);
    stageA(1, 32); stageB(1, 32);
    asm volatile("s_waitcnt vmcnt(4)" ::: "memory");
    __builtin_amdgcn_s_barrier();
    __builtin_amdgcn_sched_barrier(0);

#pragma unroll 1
    for (int t = 0; t < 30; ++t) {
        const u16* L = &lds[t & 3][0];
        const int b2 = (t + 2) & 3, kt2 = (t + 2) * 32;
        // phase A
        readB(L); readA(L, 0);
        stageA(b2, kt2);
        PH_BAR();
        mfma16(0);
        PH_BAR();
        // phase B
        readA(L, 1);
        stageB(b2, kt2);
        asm volatile("s_waitcnt vmcnt(4)" ::: "memory");  // tile t+1 resident; t+2 in flight
        PH_BAR();
        mfma16(1);
        PH_BAR();
    }
    {   // t = 30 (buf 2); tile 31's loads still in flight
        const u16* L = &lds[2][0];
        readB(L); readA(L, 0);
        PH_BAR();
        mfma16(0);
        PH_BAR();
        readA(L, 1);
        asm volatile("s_waitcnt vmcnt(0)" ::: "memory");  // tile 31 resident
        PH_BAR();
        mfma16(1);
        PH_BAR();
    }
    {   // t = 31 (buf 3)
        const u16* L = &lds[3][0];
        readB(L); readA(L, 0);
        PH_BAR();
        mfma16(0);
        PH_BAR();
        readA(L, 1);
        __builtin_amdgcn_sched_barrier(0);
        mfma16(1);
    }

    // epilogue: bf16 pack scatter + per-64col exp-sum partials
    const int cr = hi * 4, cc = lr;
    const int climit = TAIL ? 40000 : 10002;
    const int pstride = TAIL ? 628 : 160;
#pragma unroll
    for (int m = 0; m < 8; m++) {
#pragma unroll
        for (int q = 0; q < 4; q++) {
            int r = m0 + wm * 128 + m * 16 + cr + q;
            long orow = TAIL ? rowlist[r] : r;
            size_t base = TAIL ? pack_base_tail(orow) : pack_base_head(orow);
            u16* dst = outpk + base + n0 + wn * 64 + cc;
            float s = 0.f;
#pragma unroll
            for (int j = 0; j < 4; j++) {
                float v = acc[m][j][q];
                dst[j * 16] = f2bf(v);
                int col = n0 + wn * 64 + j * 16 + cc;
                s += (col < climit) ? __expf(v) : 0.f;
            }
            s += __shfl_xor(s, 1); s += __shfl_xor(s, 2);
            s += __shfl_xor(s, 4); s += __shfl_xor(s, 8);
            if (cc == 0) part[(size_t)r * pstride + (n0 >> 6) + wn] = s;
        }
    }
}

// ---------- 128x128 NT bf16 GEMM (m97 structure) for proj ----------
__global__ __launch_bounds__(256) void gemm_nt_bf16(const u16* __restrict__ A, int lda,
                                                    const u16* __restrict__ B, int ldb,
                                                    u16* __restrict__ Cb, long ldc, int K) {
    __shared__ u16 lA[128 * 32];
    __shared__ u16 lB[128 * 32];
    const int tid = threadIdx.x;
    const int lane = tid & 63, wv = tid >> 6;
    const int m0 = blockIdx.x * 128, n0 = blockIdx.y * 128;

    const u16* gA0 = A + (size_t)(m0 + (tid >> 2)) * lda + (tid & 3) * 8;
    const u16* gB0 = B + (size_t)(n0 + (tid >> 2)) * ldb + (tid & 3) * 8;
    char* dA = (char*)lA + wv * 1024;
    char* dB = (char*)lB + wv * 1024;

    f32x4 acc[4][4] = {};
    const int wm = wv >> 1, wn = wv & 1;
    const int lr = lane & 15;
    const int lk = (lane >> 4) * 8;

    for (int kt = 0; kt < K; kt += 32) {
        __syncthreads();
        gld_lds16(dA, gA0);
        gld_lds16(dA + 4096, gA0 + 64 * (size_t)lda);
        gld_lds16(dB, gB0);
        gld_lds16(dB + 4096, gB0 + 64 * (size_t)ldb);
        gA0 += 32; gB0 += 32;
        __syncthreads();

        bf16x8 af[4], bfr[4];
#pragma unroll
        for (int i = 0; i < 4; i++) {
            af[i]  = *(const bf16x8*)(lA + (wm * 64 + i * 16 + lr) * 32 + lk);
            bfr[i] = *(const bf16x8*)(lB + (wn * 64 + i * 16 + lr) * 32 + lk);
        }
#pragma unroll
        for (int i = 0; i < 4; i++)
#pragma unroll
            for (int j = 0; j < 4; j++)
                acc[i][j] = __builtin_amdgcn_mfma_f32_16x16x32_bf16(af[i], bfr[j], acc[i][j], 0, 0, 0);
    }

    const int cr = (lane >> 4) * 4;
    const int cc = lane & 15;
#pragma unroll
    for (int i = 0; i < 4; i++) {
        int rbase = m0 + wm * 64 + i * 16 + cr;
#pragma unroll
        for (int j = 0; j < 4; j++) {
            int c = n0 + wn * 64 + j * 16 + cc;
#pragma unroll
            for (int q = 0; q < 4; q++)
                Cb[(size_t)(rbase + q) * (size_t)ldc + c] = f2bf(acc[i][j][q]);
        }
    }
}

// ---------- head: reduce partials -> logZ; expand bf16 pack -> f32 lp; save stats ----------
// stats per row (8 f32): [0]=prior0(lp[9999]) [1]=prior1(lp[10000]) [2]=lp[10000] [3]=lp[10001]
__global__ __launch_bounds__(256) void head_norm(float* __restrict__ out,
                                                 float* __restrict__ stats,
                                                 const float* __restrict__ parth) {
    const int row = blockIdx.x, tid = threadIdx.x;
    float s = (tid < 160) ? parth[(size_t)row * 160 + tid] : 0.f;
#pragma unroll
    for (int o = 32; o; o >>= 1) s += __shfl_xor(s, o);
    __shared__ float red[4];
    if ((tid & 63) == 0) red[tid >> 6] = s;
    __syncthreads();
    float logZ = __logf(red[0] + red[1] + red[2] + red[3]);
    const u16* pk = (const u16*)out + pack_base_head(row);
    float* p = out + (size_t)row * 50257;
    for (int k = 0; k < 5; k++) {
        int c0 = k * 2048 + tid * 8;
        if (c0 + 8 <= 10002) {
            u16x8 xv = *(const u16x8*)(pk + c0);
#pragma unroll
            for (int z = 0; z < 8; z++) p[c0 + z] = bf2f(xv[z]) - logZ;
        } else if (c0 < 10002) {
            for (int z = 0; c0 + z < 10002; z++) p[c0 + z] = bf2f(pk[c0 + z]) - logZ;
        }
    }
    if (tid == 0) {
        float* st = stats + row * 8;
        float l0 = bf2f(pk[9999]) - logZ;
        float l1 = bf2f(pk[10000]) - logZ;
        float l2 = bf2f(pk[10001]) - logZ;
        st[0] = l0; st[1] = l1; st[2] = l1; st[3] = l2;
    }
}

// ---------- tail0: reduce partials + in-place expand+normalize / zero-fill ----------
// block b: b<cnt -> masked row rowlist[b]; b>=cnt -> unmasked row rowlist[b]
__global__ __launch_bounds__(256) void tail0_norm(float* __restrict__ out,
                                                  const int* __restrict__ rowlist,
                                                  const int* __restrict__ cntbuf,
                                                  const float* __restrict__ ST,
                                                  const float* __restrict__ PART) {
    const int b = blockIdx.x, tid = threadIdx.x;
    const int cnt = cntbuf[0];
    const long row = rowlist[b];
    float* p = out + (size_t)row * 50257 + 10000;
    __shared__ float red[4];
    if (b < cnt) {
        float s = 0.f;
        for (int c = tid; c < 628; c += 256) s += PART[(size_t)b * 628 + c];
#pragma unroll
        for (int o = 32; o; o >>= 1) s += __shfl_xor(s, o);
        if ((tid & 63) == 0) red[tid >> 6] = s;
        __syncthreads();
        float Aa = __logf(red[0] + red[1] + red[2] + red[3]) - ST[row * 8 + 0];
        const u16* src = (const u16*)out + pack_base_tail(row);
        for (int k = 0; k < 5; k++) {
            float v[4][8];
#pragma unroll
            for (int g = 0; g < 4; g++) {
                int o = 2048 * g + tid * 8;
                if (o < 8000) {
                    u16x8 xv = *(const u16x8*)(src + 8000 * k + o);
#pragma unroll
                    for (int z = 0; z < 8; z++) v[g][z] = bf2f(xv[z]);
                }
            }
            __syncthreads();
#pragma unroll
            for (int g = 0; g < 4; g++) {
                int o = 2048 * g + tid * 8;
                if (o < 8000) {
                    int e = 8000 * k + o;
#pragma unroll
                    for (int z = 0; z < 8; z++) p[e + z] = v[g][z] - Aa;
                }
            }
            __syncthreads();
        }
    } else {
        float v0 = ST[row * 8 + 2], v1 = ST[row * 8 + 3];
        for (int e = tid; e < 40000; e += 256) p[e] = 0.f;
        if (tid == 0) { p[0] = v0; p[1] = v1; }
    }
}

// ---------- tail1: tiny GEMM + log_softmax + masked write for cols [50000,50257) ----------
__global__ __launch_bounds__(256) void tail1_kernel(float* __restrict__ out,
                                                    const int* __restrict__ tgt,
                                                    const u16* __restrict__ proj,
                                                    const u16* __restrict__ t1b,
                                                    const float* __restrict__ stats) {
    const int row = blockIdx.x, tid = threadIdx.x;
    float* p = out + (size_t)row * 50257 + 50000;
    int t = tgt[row];
    if (t < 50000) {
        for (int c = tid; c < 257; c += 256) p[c] = 0.f;
        return;
    }
    __shared__ float pr[256];
    __shared__ float lg[257];
    __shared__ float red[4];
    pr[tid] = bf2f(proj[(size_t)row * 1280 + 1024 + tid]);
    __syncthreads();
    for (int c = tid; c < 257; c += 256) {
        const u16* w = t1b + c * 256;
        float acc = 0.f;
        for (int k = 0; k < 256; k++) acc += bf2f(w[k]) * pr[k];
        lg[c] = acc;
    }
    __syncthreads();
    float s = 0.f;
    for (int c = tid; c < 257; c += 256) s += __expf(lg[c]);
#pragma unroll
    for (int o = 32; o; o >>= 1) s += __shfl_xor(s, o);
    if ((tid & 63) == 0) red[tid >> 6] = s;
    __syncthreads();
    float A = __logf(red[0] + red[1] + red[2] + red[3]) - stats[row * 8 + 1];  // logZ - prior1
    for (int c = tid; c < 257; c += 256) p[c] = lg[c] - A;
}

// ---------- workspace layout (bytes) ----------
#define OFF_XI    0UL              // 2048*1024*2    = 4,194,304
#define OFF_HEADW 4194304UL        // 10240*1024*2   = 20,971,520
#define OFF_TAB   25165824UL       // 1280*1024*2    = 2,621,440
#define OFF_T0B   27787264UL       // 40192*1024*2   = 82,313,216
#define OFF_T1B   110100480UL      // 257*256*2      = 131,584
#define OFF_PROJ  110232064UL      // 2048*1280*2    = 5,242,880
#define OFF_ST    115474944UL      // 2048*8*4       = 65,536
#define OFF_PART  115540480UL      // 2048*628*4     = 5,144,576
#define OFF_PARTH 120685056UL      // 2048*160*4     = 1,310,720
#define OFF_MAP   121995776UL      // 2048*4
#define OFF_CNT   122003968UL      // 64

extern "C" void kernel_launch(void* const* d_in, const int* in_sizes, int n_in,
                              void* d_out, int out_size, void* d_ws, size_t ws_size,
                              hipStream_t stream) {
    const float* x   = (const float*)d_in[0];
    const int*   tgt = (const int*)d_in[1];
    const float* hw  = (const float*)d_in[2];
    const float* t0a = (const float*)d_in[3];
    const float* t0b = (const float*)d_in[4];
    const float* t1a = (const float*)d_in[5];
    const float* t1b = (const float*)d_in[6];
    float* out = (float*)d_out;
    char* ws = (char*)d_ws;

    u16* XI     = (u16*)(ws + OFF_XI);
    u16* HW     = (u16*)(ws + OFF_HEADW);
    u16* TAB    = (u16*)(ws + OFF_TAB);
    u16* T0B    = (u16*)(ws + OFF_T0B);
    u16* T1B    = (u16*)(ws + OFF_T1B);
    u16* PROJ   = (u16*)(ws + OFF_PROJ);
    float* ST   = (float*)(ws + OFF_ST);
    float* PART = (float*)(ws + OFF_PART);
    float* PARTH = (float*)(ws + OFF_PARTH);
    int* MAP    = (int*)(ws + OFF_MAP);
    int* CNT    = (int*)(ws + OFF_CNT);

    // 1) all converts + pads (one kernel)
    cvt_all<<<2108, 256, 0, stream>>>(x, hw, t0a, t1a, t0b, t1b, XI, HW, TAB, T0B, T1B);

    // 2) row map
    build_map<<<1, 256, 0, stream>>>(tgt, MAP, CNT);

    // 3) head GEMM (256^2 phase-pipelined): bf16 pack into out rows + exp partials
    gemm256<0><<<dim3(8, 40), 512, 0, stream>>>(XI, HW, (u16*)d_out, nullptr, nullptr, PARTH);

    // 4) head: logZ + expand to f32 lp + stats
    head_norm<<<2048, 256, 0, stream>>>(out, ST, PARTH);

    // 5) proj GEMM: [xi @ t0a.T | xi @ t1a.T] -> bf16 (2048 x 1280)
    gemm_nt_bf16<<<dim3(16, 10), 256, 0, stream>>>(XI, 1024, TAB, 1024, PROJ, 1280L, 1024);

    // 6) tail0 GEMM (256^2 phase-pipelined, rowlist-gathered A): bf16 pack + exp partials
    gemm256<1><<<dim3(8, 157), 512, 0, stream>>>(PROJ, T0B, (u16*)d_out, MAP, CNT, PART);

    // 7) fused reduce + expand/normalize (masked) / zero-fill (unmasked)
    tail0_norm<<<2048, 256, 0, stream>>>(out, MAP, CNT, ST, PART);

    // 8) tail1
    tail1_kernel<<<2048, 256, 0, stream>>>(out, tgt, PROJ, T1B, ST);
}